// Round 1
// 393.378 us; speedup vs baseline: 1.0646x; 1.0646x over previous
//
#include <hip/hip_runtime.h>
#include <stdint.h>

// ---- problem constants ----
#define DIMX 1024
#define DIM_INNER 2048
#define BATCH 4
#define SEQ 4096
#define M_TOTAL (BATCH * SEQ)   // 16384
#define N_HG (2 * DIM_INNER)    // 4096
#define NCHUNK 32               // chunks along S
#define CLEN 128                // steps per chunk

typedef unsigned short u16;
typedef __attribute__((ext_vector_type(8))) short short8;   // 8 x bf16 MFMA frag
typedef __attribute__((ext_vector_type(4))) float floatx4;  // MFMA acc

// ---- bf16 helpers (bit-level, RNE) ----
__device__ __forceinline__ float bflo(uint32_t u) { return __uint_as_float(u << 16); }
__device__ __forceinline__ float bfhi(uint32_t u) { return __uint_as_float(u & 0xffff0000u); }
__device__ __forceinline__ uint32_t f2bf_bits(float f) {
    uint32_t u = __float_as_uint(f);
    return (u + 0x7fffu + ((u >> 16) & 1u)) >> 16;  // round-to-nearest-even
}

#define GCAST(p) (const __attribute__((address_space(1))) uint32_t*)(const void*)(p)
#define LCAST(p) (__attribute__((address_space(3))) uint32_t*)(void*)(p)
// counted-vmcnt tile gate: prev tile's ds_reads drained (lgkm) BEFORE barrier so
// post-barrier DMA prefetch can't clobber in-flight reads; vmcnt(N) leaves N
// loads in flight across the barrier (T4: never drain to 0 in the main loop).
#define SYNCG(N)                                                              \
    do {                                                                      \
        asm volatile("s_waitcnt vmcnt(" #N ") lgkmcnt(0)" ::: "memory");      \
        __builtin_amdgcn_s_barrier();                                         \
    } while (0)

// ============================================================
// prep kernel: fuses x-cast + Whg transpose + Wout transpose. (unchanged)
// ============================================================
__global__ __launch_bounds__(256) void prep(const float* __restrict__ x,
                                            const float* __restrict__ Whg,
                                            const float* __restrict__ Wout,
                                            u16* __restrict__ xb,
                                            u16* __restrict__ whgt,
                                            u16* __restrict__ woutt) {
    __shared__ float tile[64][65];
    const int bid = blockIdx.x;
    const int tid = threadIdx.x;
    if (bid < 2048) {
        const int n4 = M_TOTAL * DIMX / 4;
        const float4* in4 = (const float4*)x;
        ushort4* out4 = (ushort4*)xb;
        for (int i = bid * 256 + tid; i < n4; i += 2048 * 256) {
            float4 v = in4[i];
            ushort4 o;
            o.x = (u16)f2bf_bits(v.x);
            o.y = (u16)f2bf_bits(v.y);
            o.z = (u16)f2bf_bits(v.z);
            o.w = (u16)f2bf_bits(v.w);
            out4[i] = o;
        }
        return;
    }
    const float* in;
    u16* out;
    int R, C, tb;
    if (bid < 3072) {
        in = Whg; out = whgt; R = DIMX; C = N_HG; tb = bid - 2048;
    } else {
        in = Wout; out = woutt; R = DIM_INNER; C = DIMX; tb = bid - 3072;
    }
    const int tilesx = C / 64;
    const int c0 = (tb % tilesx) * 64, r0 = (tb / tilesx) * 64;
    const int tx = tid & 63, ty = tid >> 6;  // 64 x 4
#pragma unroll
    for (int i = ty; i < 64; i += 4)
        tile[i][tx] = in[(size_t)(r0 + i) * C + c0 + tx];
    __syncthreads();
#pragma unroll
    for (int i = ty; i < 64; i += 4)
        out[(size_t)(c0 + i) * R + r0 + tx] = (u16)f2bf_bits(tile[tx][i]);
}

// ============================================================
// GEMM1 fused (R10): deep-pipelined. BM=256 rows x BN=128 channels x {h,g},
// BK=32, 4 LDS buffers (128 KB), 512 thr / 8 waves (2M x 4N; wave =
// 128 rows x 32 ch, acch+accg = 128 VGPR). Prefetch 3 tiles ahead,
// 4 global_load_lds per tile, gate vmcnt(8) -> loads live across barriers.
// Epilogue: (a,v) pack + in-block 2-chunk summary. grid (16, 64).
// ============================================================
__global__ __launch_bounds__(512, 2) void gemm1_k(const u16* __restrict__ A,
                                                  const u16* __restrict__ Bt,
                                                  uint32_t* __restrict__ av,
                                                  float2* __restrict__ sumAV) {
    // per buffer q (32 KB): As [256][32] @ q*16384, Bh [128][32] @ +8192, Bg @ +12288
    __shared__ alignas(16) u16 smem[65536];  // 128 KB
    const int tid = threadIdx.x;
    const int lane = tid & 63;
    const int wave = tid >> 6;
    const int wr = wave >> 2;  // row half (0/1) -> 128 rows
    const int wc = wave & 3;   // channel quarter -> 32 ch
    const size_t m0 = (size_t)blockIdx.y * 256;
    const int n0 = blockIdx.x * 128;

    floatx4 acch[8][2], accg[8][2];
#pragma unroll
    for (int i = 0; i < 8; ++i)
#pragma unroll
        for (int j = 0; j < 2; ++j) {
            acch[i][j] = (floatx4){0.f, 0.f, 0.f, 0.f};
            accg[i][j] = (floatx4){0.f, 0.f, 0.f, 0.f};
        }

    // staging: global side carries the XOR k-swizzle, LDS stays linear.
    const int srow = lane >> 2;
    const int ssw = ((lane & 3) ^ ((srow >> 1) & 3)) * 8;
    const u16* Ag = A + (m0 + wave * 16 + srow) * DIMX + ssw;
    const u16* Bhg = Bt + ((size_t)(n0 + wave * 16 + srow)) * DIMX + ssw;
    const u16* Bgg = Bt + ((size_t)(DIM_INNER + n0 + wave * 16 + srow)) * DIMX + ssw;

    const int fr = lane & 15;
    const int koff = ((lane >> 4) ^ ((fr >> 1) & 3)) * 8;

#define STAGE1(u)                                                                          \
    do {                                                                                   \
        const int q_ = (u) & 3;                                                            \
        const int k0_ = (u) * 32;                                                          \
        u16* b_ = smem + q_ * 16384;                                                       \
        __builtin_amdgcn_global_load_lds(GCAST(Ag + k0_), LCAST(b_ + wave * 512), 16, 0, 0);                \
        __builtin_amdgcn_global_load_lds(GCAST(Ag + (size_t)128 * DIMX + k0_),             \
                                         LCAST(b_ + 4096 + wave * 512), 16, 0, 0);         \
        __builtin_amdgcn_global_load_lds(GCAST(Bhg + k0_), LCAST(b_ + 8192 + wave * 512), 16, 0, 0);        \
        __builtin_amdgcn_global_load_lds(GCAST(Bgg + k0_), LCAST(b_ + 12288 + wave * 512), 16, 0, 0);       \
    } while (0)

#define TILE1(u, DOSTAGE)                                                                  \
    do {                                                                                   \
        const u16* As_ = smem + ((u) & 3) * 16384;                                         \
        const u16* Bh_ = As_ + 8192;                                                       \
        const u16* Bg_ = As_ + 12288;                                                      \
        short8 af_[8], bh_[2], bg_[2];                                                     \
        _Pragma("unroll") for (int j_ = 0; j_ < 2; ++j_) {                                 \
            bh_[j_] = *(const short8*)(Bh_ + (wc * 32 + j_ * 16 + fr) * 32 + koff);        \
            bg_[j_] = *(const short8*)(Bg_ + (wc * 32 + j_ * 16 + fr) * 32 + koff);        \
        }                                                                                  \
        _Pragma("unroll") for (int i_ = 0; i_ < 8; ++i_)                                   \
            af_[i_] = *(const short8*)(As_ + (wr * 128 + i_ * 16 + fr) * 32 + koff);       \
        if (DOSTAGE) STAGE1((u) + 3);                                                      \
        __builtin_amdgcn_s_setprio(1);                                                     \
        _Pragma("unroll") for (int i_ = 0; i_ < 8; ++i_)                                   \
            _Pragma("unroll") for (int j_ = 0; j_ < 2; ++j_) {                             \
                acch[i_][j_] =                                                             \
                    __builtin_amdgcn_mfma_f32_16x16x32_bf16(af_[i_], bh_[j_], acch[i_][j_], 0, 0, 0); \
                accg[i_][j_] =                                                             \
                    __builtin_amdgcn_mfma_f32_16x16x32_bf16(af_[i_], bg_[j_], accg[i_][j_], 0, 0, 0); \
            }                                                                              \
        __builtin_amdgcn_s_setprio(0);                                                     \
    } while (0)

    // prologue: 3 tiles in flight (12 loads)
    STAGE1(0);
    STAGE1(1);
    STAGE1(2);
    // steady: gate vmcnt(8) = tiles t+1,t+2 stay in flight across the barrier
    for (int t = 0; t < 29; ++t) {
        SYNCG(8);
        TILE1(t, 1);
    }
    SYNCG(8);
    TILE1(29, 0);
    SYNCG(4);
    TILE1(30, 0);
    SYNCG(0);
    TILE1(31, 0);
    __syncthreads();  // staging LDS dead; reuse as avl [256][128] u32 = 128 KB

    uint32_t* avl = (uint32_t*)smem;
    const int r0row = (lane >> 4) * 4;
#pragma unroll
    for (int i = 0; i < 8; ++i) {
#pragma unroll
        for (int r = 0; r < 4; ++r) {
            const int row = wr * 128 + i * 16 + r0row + r;
#pragma unroll
            for (int j = 0; j < 2; ++j) {
                const int col = wc * 32 + j * 16 + fr;
                float h = acch[i][j][r];
                float g = accg[i][j][r];
                g = fminf(fmaxf(g, -30.f), 30.f);
                float e = __expf(-g);
                float z = 1.f / (1.f + e);
                float a = e * z;                       // 1 - sigmoid(g)
                float v = z * (fmaxf(h, 0.f) + 0.5f);  // sigmoid(g)*(relu(h)+0.5)
                uint32_t pk = f2bf_bits(a) | (f2bf_bits(v) << 16);
                avl[row * 128 + col] = pk;
                av[(m0 + row) * 2048 + n0 + col] = pk;
            }
        }
    }
    __syncthreads();

    // in-block chunk-summary scan: block covers 2 chunks of 128 rows
    const int chl = tid >> 8;    // chunk-local 0/1
    const int t2 = tid & 255;
    const int col = t2 & 127;
    const int rlo = (t2 >> 7) * 64;
    float Aa = 1.f, Vv = 0.f;
#pragma unroll 8
    for (int j = 0; j < 64; ++j) {
        uint32_t pk = avl[(chl * 128 + rlo + j) * 128 + col];
        float a = bflo(pk), v = bfhi(pk);
        Vv = fmaf(a, Vv, v);
        Aa *= a;
    }
    __syncthreads();
    if (rlo == 0) {
        avl[chl * 256 + col] = __float_as_uint(Aa);
        avl[chl * 256 + 128 + col] = __float_as_uint(Vv);
    }
    __syncthreads();
    if (rlo != 0) {
        float Al = __uint_as_float(avl[chl * 256 + col]);
        float Vl = __uint_as_float(avl[chl * 256 + 128 + col]);
        float At = Al * Aa;
        float Vt = fmaf(Aa, Vl, Vv);
        const int chunk = (int)(m0 >> 7) + chl;  // global chunk id = b*32+ch
        sumAV[(size_t)chunk * 2048 + n0 + col] = (float2){At, Vt};
    }
#undef STAGE1
#undef TILE1
}

// ============================================================
// GEMM2 (R10): 256x256 tile, BK=32, same 4-buffer counted-vmcnt pipeline.
// 512 thr / 8 waves (2M x 4N; wave = 128x64, acc[8][4] = 128 VGPR).
// grid (1024/256=4, 16384/256=64) = 256 blocks = one block per CU.
// ============================================================
__global__ __launch_bounds__(512, 2) void gemm2_k(const u16* __restrict__ A,
                                                  const u16* __restrict__ Bt,
                                                  float* __restrict__ C) {
    const int N = DIMX, K = DIM_INNER;
    // per buffer q (32 KB): As [256][32] @ q*16384, Bs [256][32] @ +8192
    __shared__ alignas(16) u16 smem[65536];  // 128 KB
    const int tid = threadIdx.x;
    const int lane = tid & 63;
    const int wave = tid >> 6;
    const int wr = wave >> 2;
    const int wc = wave & 3;
    const size_t m0 = (size_t)blockIdx.y * 256;
    const size_t n0 = (size_t)blockIdx.x * 256;

    floatx4 acc[8][4];
#pragma unroll
    for (int i = 0; i < 8; ++i)
#pragma unroll
        for (int j = 0; j < 4; ++j) acc[i][j] = (floatx4){0.f, 0.f, 0.f, 0.f};

    const int srow = lane >> 2;
    const int ssw = ((lane & 3) ^ ((srow >> 1) & 3)) * 8;
    const u16* Ag = A + (m0 + wave * 16 + srow) * K + ssw;
    const u16* Bg2 = Bt + (n0 + wave * 16 + srow) * K + ssw;

    const int fr = lane & 15;
    const int koff = ((lane >> 4) ^ ((fr >> 1) & 3)) * 8;

#define STAGE2(u)                                                                          \
    do {                                                                                   \
        const int q_ = (u) & 3;                                                            \
        const int k0_ = (u) * 32;                                                          \
        u16* b_ = smem + q_ * 16384;                                                       \
        __builtin_amdgcn_global_load_lds(GCAST(Ag + k0_), LCAST(b_ + wave * 512), 16, 0, 0);            \
        __builtin_amdgcn_global_load_lds(GCAST(Ag + (size_t)128 * K + k0_),                \
                                         LCAST(b_ + 4096 + wave * 512), 16, 0, 0);         \
        __builtin_amdgcn_global_load_lds(GCAST(Bg2 + k0_), LCAST(b_ + 8192 + wave * 512), 16, 0, 0);    \
        __builtin_amdgcn_global_load_lds(GCAST(Bg2 + (size_t)128 * K + k0_),               \
                                         LCAST(b_ + 12288 + wave * 512), 16, 0, 0);        \
    } while (0)

#define TILE2(u, DOSTAGE)                                                                  \
    do {                                                                                   \
        const u16* As_ = smem + ((u) & 3) * 16384;                                         \
        const u16* Bs_ = As_ + 8192;                                                       \
        short8 af_[8], bf_[4];                                                             \
        _Pragma("unroll") for (int j_ = 0; j_ < 4; ++j_)                                   \
            bf_[j_] = *(const short8*)(Bs_ + (wc * 64 + j_ * 16 + fr) * 32 + koff);        \
        _Pragma("unroll") for (int i_ = 0; i_ < 8; ++i_)                                   \
            af_[i_] = *(const short8*)(As_ + (wr * 128 + i_ * 16 + fr) * 32 + koff);       \
        if (DOSTAGE) STAGE2((u) + 3);                                                      \
        __builtin_amdgcn_s_setprio(1);                                                     \
        _Pragma("unroll") for (int i_ = 0; i_ < 8; ++i_)                                   \
            _Pragma("unroll") for (int j_ = 0; j_ < 4; ++j_)                               \
                acc[i_][j_] =                                                              \
                    __builtin_amdgcn_mfma_f32_16x16x32_bf16(af_[i_], bf_[j_], acc[i_][j_], 0, 0, 0); \
        __builtin_amdgcn_s_setprio(0);                                                     \
    } while (0)

    STAGE2(0);
    STAGE2(1);
    STAGE2(2);
    for (int t = 0; t < 61; ++t) {  // K/32 = 64 tiles; stage t+3 <= 63
        SYNCG(8);
        TILE2(t, 1);
    }
    SYNCG(8);
    TILE2(61, 0);
    SYNCG(4);
    TILE2(62, 0);
    SYNCG(0);
    TILE2(63, 0);

    const int r0row = (lane >> 4) * 4;
#pragma unroll
    for (int i = 0; i < 8; ++i)
#pragma unroll
        for (int r = 0; r < 4; ++r) {
            size_t row = m0 + wr * 128 + i * 16 + r0row + r;
#pragma unroll
            for (int j = 0; j < 4; ++j) {
                size_t col = n0 + wc * 64 + j * 16 + fr;
                C[row * N + col] = acc[i][j][r];
            }
        }
#undef STAGE2
#undef TILE2
}

// ============================================================
// Phase B: carry scan over 32 chunk summaries per (batch, channel) chain.
// ============================================================
__global__ __launch_bounds__(64) void scan_carry(const float2* __restrict__ sumAV,
                                                 float* __restrict__ carry) {
    const int g = blockIdx.x * 64 + threadIdx.x;  // 0..8191
    const int b = g >> 11, c = g & 2047;
    float h = 0.f;
#pragma unroll 8
    for (int ch = 0; ch < NCHUNK; ++ch) {
        float2 s = sumAV[(size_t)(b * NCHUNK + ch) * 2048 + c];
        carry[(size_t)(b * NCHUNK + ch) * 2048 + c] = h;
        h = fmaf(s.x, h, s.y);
    }
}

// ============================================================
// Phase C: replay chunk from packed (a,v), carry-in, emit h bf16.
// batch-4 prefetch (4 x 8B loads in flight per thread).
// grid (4, NCHUNK, BATCH) x 256; thread -> 2 channels.
// ============================================================
__global__ __launch_bounds__(256) void scan_apply(const uint32_t* __restrict__ av,
                                                  const float* __restrict__ carry,
                                                  uint32_t* __restrict__ hbuf) {
    const int b = blockIdx.z, ch = blockIdx.y;
    const int c2 = blockIdx.x * 256 + threadIdx.x;  // channel-pair 0..1023
    const size_t rowbase = (size_t)b * SEQ + (size_t)ch * CLEN;
    const uint32_t* p = av + rowbase * 2048 + c2 * 2;
    uint32_t* q = hbuf + rowbase * 1024 + c2;
    const float2 cin = ((const float2*)carry)[(size_t)(b * NCHUNK + ch) * 1024 + c2];
    float h0 = cin.x, h1 = cin.y;

    uint2 buf[4];
#pragma unroll
    for (int t = 0; t < 4; ++t) buf[t] = *(const uint2*)(p + (size_t)t * 2048);

    for (int j0 = 0; j0 < CLEN; j0 += 4) {
        uint2 nxt[4];
        if (j0 + 4 < CLEN) {
#pragma unroll
            for (int t = 0; t < 4; ++t)
                nxt[t] = *(const uint2*)(p + (size_t)(j0 + 4 + t) * 2048);
        }
#pragma unroll
        for (int t = 0; t < 4; ++t) {
            float a0 = bflo(buf[t].x), v0 = bfhi(buf[t].x);
            float a1 = bflo(buf[t].y), v1 = bfhi(buf[t].y);
            h0 = fmaf(a0, h0, v0);
            h1 = fmaf(a1, h1, v1);
            q[(size_t)(j0 + t) * 1024] = f2bf_bits(h0) | (f2bf_bits(h1) << 16);
        }
#pragma unroll
        for (int t = 0; t < 4; ++t) buf[t] = nxt[t];
    }
}

// ============================================================
extern "C" void kernel_launch(void* const* d_in, const int* in_sizes, int n_in,
                              void* d_out, int out_size, void* d_ws, size_t ws_size,
                              hipStream_t stream) {
    const float* x = (const float*)d_in[0];     // [16384,1024]
    const float* Whg = (const float*)d_in[1];   // [1024,4096]
    const float* Wout = (const float*)d_in[2];  // [2048,1024]

    char* ws = (char*)d_ws;
    size_t off = 0;
    u16* xb = (u16*)(ws + off);        off += (size_t)M_TOTAL * DIMX * 2;          // 33.6 MB
    u16* whgt = (u16*)(ws + off);      off += (size_t)N_HG * DIMX * 2;             // 8.4 MB
    u16* woutt = (u16*)(ws + off);     off += (size_t)DIMX * DIM_INNER * 2;        // 4.2 MB
    uint32_t* av = (uint32_t*)(ws + off); off += (size_t)M_TOTAL * DIM_INNER * 4;  // 134.2 MB
    uint32_t* hbuf = (uint32_t*)(ws + off); off += (size_t)M_TOTAL * DIM_INNER * 2; // 67.1 MB
    float2* sumAV = (float2*)(ws + off); off += (size_t)BATCH * NCHUNK * DIM_INNER * 8; // 2.1 MB
    // carry (1 MB) aliases whgt: whgt dead after gemm1_k (stream-ordered).
    float* carry = (float*)whgt;

    // 1. fused prep
    prep<<<2048 + 1024 + 512, 256, 0, stream>>>(x, Whg, Wout, xb, whgt, woutt);

    // 2. GEMM1 fused (deep pipeline): av + per-chunk summaries
    gemm1_k<<<dim3(16, 64), 512, 0, stream>>>(xb, whgt, av, sumAV);

    // 3. carry scan (chains of 32) + replay
    scan_carry<<<128, 64, 0, stream>>>(sumAV, carry);
    scan_apply<<<dim3(4, NCHUNK, BATCH), 256, 0, stream>>>(av, carry, hbuf);

    // 4. GEMM2 (deep pipeline): out = h @ Wout (fp32 out), 256x256 tiles
    gemm2_k<<<dim3(DIMX / 256, M_TOTAL / 256), 512, 0, stream>>>((const u16*)hbuf, woutt, (float*)d_out);
}

// Round 3
// 375.960 us; speedup vs baseline: 1.1140x; 1.0463x over previous
//
#include <hip/hip_runtime.h>
#include <stdint.h>

// ---- problem constants ----
#define DIMX 1024
#define DIM_INNER 2048
#define BATCH 4
#define SEQ 4096
#define M_TOTAL (BATCH * SEQ)   // 16384
#define N_HG (2 * DIM_INNER)    // 4096
#define NCHUNK 32               // chunks along S
#define CLEN 128                // steps per chunk

typedef unsigned short u16;
typedef __attribute__((ext_vector_type(8))) short short8;   // 8 x bf16 MFMA frag
typedef __attribute__((ext_vector_type(4))) float floatx4;  // MFMA acc

// ---- bf16 helpers (bit-level, RNE) ----
__device__ __forceinline__ float bflo(uint32_t u) { return __uint_as_float(u << 16); }
__device__ __forceinline__ float bfhi(uint32_t u) { return __uint_as_float(u & 0xffff0000u); }
__device__ __forceinline__ uint32_t f2bf_bits(float f) {
    uint32_t u = __float_as_uint(f);
    return (u + 0x7fffu + ((u >> 16) & 1u)) >> 16;  // round-to-nearest-even
}

#define GCAST(p) (const __attribute__((address_space(1))) uint32_t*)(const void*)(p)
#define LCAST(p) (__attribute__((address_space(3))) uint32_t*)(void*)(p)
// raw barrier + IR-level fence (plain LDS loads may not cross)
#define BAR()                                          \
    do {                                               \
        __builtin_amdgcn_s_barrier();                  \
        asm volatile("" ::: "memory");                 \
    } while (0)
// drain this wave's ds_reads before the phase's MFMA + pin scheduling (rule #18)
#define LGKM0()                                                  \
    do {                                                         \
        asm volatile("s_waitcnt lgkmcnt(0)" ::: "memory");       \
        __builtin_amdgcn_sched_barrier(0);                       \
    } while (0)
#define VMCNT_(n) asm volatile("s_waitcnt vmcnt(" #n ")" ::: "memory")
#define VMCNT(n) VMCNT_(n)

// ============================================================
// prep kernel: fuses x-cast + Whg transpose + Wout transpose. (unchanged)
// ============================================================
__global__ __launch_bounds__(256) void prep(const float* __restrict__ x,
                                            const float* __restrict__ Whg,
                                            const float* __restrict__ Wout,
                                            u16* __restrict__ xb,
                                            u16* __restrict__ whgt,
                                            u16* __restrict__ woutt) {
    __shared__ float tile[64][65];
    const int bid = blockIdx.x;
    const int tid = threadIdx.x;
    if (bid < 2048) {
        const int n4 = M_TOTAL * DIMX / 4;
        const float4* in4 = (const float4*)x;
        ushort4* out4 = (ushort4*)xb;
        for (int i = bid * 256 + tid; i < n4; i += 2048 * 256) {
            float4 v = in4[i];
            ushort4 o;
            o.x = (u16)f2bf_bits(v.x);
            o.y = (u16)f2bf_bits(v.y);
            o.z = (u16)f2bf_bits(v.z);
            o.w = (u16)f2bf_bits(v.w);
            out4[i] = o;
        }
        return;
    }
    const float* in;
    u16* out;
    int R, C, tb;
    if (bid < 3072) {
        in = Whg; out = whgt; R = DIMX; C = N_HG; tb = bid - 2048;
    } else {
        in = Wout; out = woutt; R = DIM_INNER; C = DIMX; tb = bid - 3072;
    }
    const int tilesx = C / 64;
    const int c0 = (tb % tilesx) * 64, r0 = (tb / tilesx) * 64;
    const int tx = tid & 63, ty = tid >> 6;  // 64 x 4
#pragma unroll
    for (int i = ty; i < 64; i += 4)
        tile[i][tx] = in[(size_t)(r0 + i) * C + c0 + tx];
    __syncthreads();
#pragma unroll
    for (int i = ty; i < 64; i += 4)
        out[(size_t)(c0 + i) * R + r0 + tx] = (u16)f2bf_bits(tile[tx][i]);
}

// ============================================================
// GEMM1 fused (R12 = R11 resubmit; R11 bench was an infra failure).
// 8-phase 256-wide template (T2+T3+T4+T5).
// BM=256 rows x BN=128 ch x {h,g}, BK=64, 2 LDS buffers (2x64KB),
// 512 thr / 8 waves (wr=wave>>2 row-half, wc=wave&3 ch-quarter).
// Per K-tile: 4 phases, 16 MFMA each (quadrants {mh0,mh1}x{h,g}).
// LDS per buf: A [256][64] @0, B [256][64] @16384 (Bh rows 0-127, Bg 128-255),
// slot'=slot^(row&7) XOR swizzle, applied on global src AND ds_read (rule #21).
// Stage slots (iter i, t=2i, X=buf0, Y=buf1):
//  ph1: A1(t+1)->Y   [Y-A last read prev ph7, drained]
//  ph2: Bh(t+2)->X   [X-Bh read ph1]     ph3: Bg(t+2)->X  [read ph2]
//  ph4: A0(t+2)->X   [X-A read ph1,ph3]  ph5: A1(t+2)->X
//  ph6: Bh(t+3)->Y   [Y-Bh read ph5]     ph7: Bg(t+3)->Y  [read ph6]
//  ph8: A0(t+3)->Y   [Y-A read ph5,ph7]
// Gates vmcnt(6) at ph4 (covers tile t+1 halves incl. A1@ph1) and ph8
// (covers tile t+2 halves: Bh@ph2..A1@ph5). grid (16, 64).
// ============================================================
__global__ __launch_bounds__(512, 2) void gemm1_k(const u16* __restrict__ A,
                                                  const u16* __restrict__ Bt,
                                                  uint32_t* __restrict__ av,
                                                  float2* __restrict__ sumAV) {
    __shared__ alignas(16) u16 smem16[65536];  // 128 KB
    const int tid = threadIdx.x;
    const int lane = tid & 63;
    const int w = tid >> 6;
    const int wr = w >> 2;
    const int wc = w & 3;
    const size_t m0 = (size_t)blockIdx.y * 256;
    const int n0 = blockIdx.x * 128;
#define X1 0
#define Y1 32768

    floatx4 acch[8][2], accg[8][2];
#pragma unroll
    for (int i = 0; i < 8; ++i)
#pragma unroll
        for (int j = 0; j < 2; ++j) {
            acch[i][j] = (floatx4){0.f, 0.f, 0.f, 0.f};
            accg[i][j] = (floatx4){0.f, 0.f, 0.f, 0.f};
        }

    // fragment addressing (u16 indices); row stride 64 u16, slot = 8 u16 (16B)
    const int fr = lane & 15;
    const int kb = lane >> 4;
    const int sw0 = kb ^ (fr & 7);                       // swizzled slot, kstep 0
    const int a0 = (wr * 128 + fr) * 64 + sw0 * 8;       // kstep1 = a0 ^ 32
    const int a1 = a0 ^ 32;
    const int b0 = 16384 + (wc * 32 + fr) * 64 + sw0 * 8;
    const int b1 = b0 ^ 32;

    // staging: lane covers (row = 8w + lane>>3, slot' = lane&7); global slot
    // = slot' ^ (row&7) = (lane&7)^(lane>>3). LDS dest stays linear.
    const int sr = lane >> 3;
    const int sswz = (lane & 7) ^ sr;
    const u16* pA = A + (m0 + w * 8 + sr) * DIMX + sswz * 8;
    const u16* pBh = Bt + ((size_t)(n0 + w * 8 + sr)) * DIMX + sswz * 8;
    const u16* pBg = pBh + (size_t)DIM_INNER * DIMX;

#define ST1A(bufb, kt, h, l)                                                        \
    __builtin_amdgcn_global_load_lds(                                               \
        GCAST(pA + (size_t)((h) * 128 + (l) * 64) * DIMX + (kt) * 64),              \
        LCAST(smem16 + (bufb) + (h) * 8192 + (l) * 4096 + w * 512), 16, 0, 0)
#define ST1H(bufb, kt, l)                                                           \
    __builtin_amdgcn_global_load_lds(                                               \
        GCAST(pBh + (size_t)((l) * 64) * DIMX + (kt) * 64),                         \
        LCAST(smem16 + (bufb) + 16384 + (l) * 4096 + w * 512), 16, 0, 0)
#define ST1G(bufb, kt, l)                                                           \
    __builtin_amdgcn_global_load_lds(                                               \
        GCAST(pBg + (size_t)((l) * 64) * DIMX + (kt) * 64),                         \
        LCAST(smem16 + (bufb) + 24576 + (l) * 4096 + w * 512), 16, 0, 0)

#define LDS8(idx) (*(const short8*)(smem16 + (idx)))
    short8 af[2][4], bh[2][2], bg[2][2];
#define RDA1(bufb, mh)                                                  \
    do {                                                                \
        _Pragma("unroll") for (int i_ = 0; i_ < 4; ++i_) {              \
            af[0][i_] = LDS8((bufb) + a0 + ((mh) * 4 + i_) * 1024);     \
            af[1][i_] = LDS8((bufb) + a1 + ((mh) * 4 + i_) * 1024);     \
        }                                                               \
    } while (0)
#define RDBH1(bufb)                                                     \
    do {                                                                \
        _Pragma("unroll") for (int j_ = 0; j_ < 2; ++j_) {              \
            bh[0][j_] = LDS8((bufb) + b0 + j_ * 1024);                  \
            bh[1][j_] = LDS8((bufb) + b1 + j_ * 1024);                  \
        }                                                               \
    } while (0)
#define RDBG1(bufb)                                                     \
    do {                                                                \
        _Pragma("unroll") for (int j_ = 0; j_ < 2; ++j_) {              \
            bg[0][j_] = LDS8((bufb) + b0 + 8192 + j_ * 1024);           \
            bg[1][j_] = LDS8((bufb) + b1 + 8192 + j_ * 1024);           \
        }                                                               \
    } while (0)
#define MM1(ACC, IB, BF)                                                                     \
    do {                                                                                     \
        __builtin_amdgcn_s_setprio(1);                                                       \
        _Pragma("unroll") for (int i_ = 0; i_ < 4; ++i_)                                     \
            _Pragma("unroll") for (int j_ = 0; j_ < 2; ++j_) {                               \
            ACC[(IB) + i_][j_] = __builtin_amdgcn_mfma_f32_16x16x32_bf16(                    \
                af[0][i_], BF[0][j_], ACC[(IB) + i_][j_], 0, 0, 0);                          \
            ACC[(IB) + i_][j_] = __builtin_amdgcn_mfma_f32_16x16x32_bf16(                    \
                af[1][i_], BF[1][j_], ACC[(IB) + i_][j_], 0, 0, 0);                          \
        }                                                                                    \
        __builtin_amdgcn_s_setprio(0);                                                       \
    } while (0)

#define ITER1(t, FULL, G4, G8)                                                               \
    do {                                                                                     \
        /* ph1: q(mh0,h) of tile t (X) */                                                    \
        RDA1(X1, 0); RDBH1(X1);                                                              \
        ST1A(Y1, (t) + 1, 1, 0); ST1A(Y1, (t) + 1, 1, 1);                                    \
        BAR(); LGKM0(); MM1(acch, 0, bh); BAR();                                             \
        /* ph2: q(mh0,g) */                                                                  \
        RDBG1(X1);                                                                           \
        if (FULL) { ST1H(X1, (t) + 2, 0); ST1H(X1, (t) + 2, 1); }                            \
        BAR(); LGKM0(); MM1(accg, 0, bg); BAR();                                             \
        /* ph3: q(mh1,h) */                                                                  \
        RDA1(X1, 1);                                                                         \
        if (FULL) { ST1G(X1, (t) + 2, 0); ST1G(X1, (t) + 2, 1); }                            \
        BAR(); LGKM0(); MM1(acch, 4, bh); BAR();                                             \
        /* ph4: q(mh1,g); gate */                                                            \
        if (FULL) { ST1A(X1, (t) + 2, 0, 0); ST1A(X1, (t) + 2, 0, 1); }                      \
        VMCNT(G4); BAR(); MM1(accg, 4, bg); BAR();                                           \
        /* ph5: q(mh0,h) of tile t+1 (Y) */                                                  \
        RDA1(Y1, 0); RDBH1(Y1);                                                              \
        if (FULL) { ST1A(X1, (t) + 2, 1, 0); ST1A(X1, (t) + 2, 1, 1); }                      \
        BAR(); LGKM0(); MM1(acch, 0, bh); BAR();                                             \
        /* ph6: q(mh0,g) */                                                                  \
        RDBG1(Y1);                                                                           \
        if (FULL) { ST1H(Y1, (t) + 3, 0); ST1H(Y1, (t) + 3, 1); }                            \
        BAR(); LGKM0(); MM1(accg, 0, bg); BAR();                                             \
        /* ph7: q(mh1,h) */                                                                  \
        RDA1(Y1, 1);                                                                         \
        if (FULL) { ST1G(Y1, (t) + 3, 0); ST1G(Y1, (t) + 3, 1); }                            \
        BAR(); LGKM0(); MM1(acch, 4, bh); BAR();                                             \
        /* ph8: q(mh1,g); gate */                                                            \
        if (FULL) { ST1A(Y1, (t) + 3, 0, 0); ST1A(Y1, (t) + 3, 0, 1); }                      \
        VMCNT(G8); BAR(); MM1(accg, 4, bg); BAR();                                           \
    } while (0)

    // prologue: 7 half-tiles; vmcnt(6) -> tile0's 4 halves landed
    ST1H(X1, 0, 0); ST1H(X1, 0, 1);        // Bh(0)
    ST1G(X1, 0, 0); ST1G(X1, 0, 1);        // Bg(0)
    ST1A(X1, 0, 0, 0); ST1A(X1, 0, 0, 1);  // A0(0)
    ST1A(X1, 0, 1, 0); ST1A(X1, 0, 1, 1);  // A1(0)
    ST1H(Y1, 1, 0); ST1H(Y1, 1, 1);        // Bh(1)
    ST1G(Y1, 1, 0); ST1G(Y1, 1, 1);        // Bg(1)
    ST1A(Y1, 1, 0, 0); ST1A(Y1, 1, 0, 1);  // A0(1)
    VMCNT(6); BAR();
#pragma unroll 1
    for (int it = 0; it < 7; ++it) ITER1(2 * it, 1, 6, 6);
    ITER1(14, 0, 0, 6);  // tiles 14,15; ph1 stages A1(15); ph4 drains all

    __syncthreads();  // staging LDS dead; reuse as avl [256][128] u32 = 128 KB

    uint32_t* avl = (uint32_t*)smem16;
    const int r0row = (lane >> 4) * 4;
#pragma unroll
    for (int i = 0; i < 8; ++i) {
#pragma unroll
        for (int r = 0; r < 4; ++r) {
            const int row = wr * 128 + i * 16 + r0row + r;
#pragma unroll
            for (int j = 0; j < 2; ++j) {
                const int col = wc * 32 + j * 16 + fr;
                float h = acch[i][j][r];
                float g = accg[i][j][r];
                g = fminf(fmaxf(g, -30.f), 30.f);
                float e = __expf(-g);
                float z = 1.f / (1.f + e);
                float a = e * z;                       // 1 - sigmoid(g)
                float v = z * (fmaxf(h, 0.f) + 0.5f);  // sigmoid(g)*(relu(h)+0.5)
                uint32_t pk = f2bf_bits(a) | (f2bf_bits(v) << 16);
                avl[row * 128 + col] = pk;
                av[(m0 + row) * 2048 + n0 + col] = pk;
            }
        }
    }
    __syncthreads();

    // in-block chunk-summary scan: block covers 2 chunks of 128 rows
    const int chl = tid >> 8;  // chunk-local 0/1
    const int t2 = tid & 255;
    const int col = t2 & 127;
    const int rlo = (t2 >> 7) * 64;
    float Aa = 1.f, Vv = 0.f;
#pragma unroll 8
    for (int j = 0; j < 64; ++j) {
        uint32_t pk = avl[(chl * 128 + rlo + j) * 128 + col];
        float a = bflo(pk), v = bfhi(pk);
        Vv = fmaf(a, Vv, v);
        Aa *= a;
    }
    __syncthreads();
    if (rlo == 0) {
        avl[chl * 256 + col] = __float_as_uint(Aa);
        avl[chl * 256 + 128 + col] = __float_as_uint(Vv);
    }
    __syncthreads();
    if (rlo != 0) {
        float Al = __uint_as_float(avl[chl * 256 + col]);
        float Vl = __uint_as_float(avl[chl * 256 + 128 + col]);
        float At = Al * Aa;
        float Vt = fmaf(Aa, Vl, Vv);
        const int chunk = (int)(m0 >> 7) + chl;  // global chunk id = b*32+ch
        sumAV[(size_t)chunk * 2048 + n0 + col] = (float2){At, Vt};
    }
#undef ST1A
#undef ST1H
#undef ST1G
#undef RDA1
#undef RDBH1
#undef RDBG1
#undef MM1
#undef ITER1
}

// ============================================================
// GEMM2 (R12 = R11 resubmit): 8-phase 256x256 template. BK=64, 2x64KB buffers,
// 512 thr / 8 waves; wave = 128 rows x 64 cols, acc[8][4] = 128 VGPR.
// Quadrants {mh}x{nh}. Stage slots (iter i, t=2i):
//  ph1: A0(t+1)->Y  ph2: A1(t+1)->Y   [Y-A last read prev ph7]
//  ph3: B0(t+2)->X  ph4: B1(t+2)->X   [X-B read ph1,ph2]
//  ph5: A0(t+2)->X  ph6: A1(t+2)->X   [X-A read ph1,ph3]
//  ph7: B0(t+3)->Y  ph8: B1(t+3)->Y   [Y-B read ph5,ph6]
// Gates vmcnt(4) at ph4 (covers through ph2: A(t+1)) and ph8 (through
// ph6: A(t+2)). grid (4, 64) = 256 blocks.
// ============================================================
__global__ __launch_bounds__(512, 2) void gemm2_k(const u16* __restrict__ A,
                                                  const u16* __restrict__ Bt,
                                                  float* __restrict__ C) {
    const int N = DIMX, K = DIM_INNER;
    __shared__ alignas(16) u16 smem16[65536];  // 128 KB
    const int tid = threadIdx.x;
    const int lane = tid & 63;
    const int w = tid >> 6;
    const int wr = w >> 2;
    const int wc = w & 3;
    const size_t m0 = (size_t)blockIdx.y * 256;
    const size_t n0 = (size_t)blockIdx.x * 256;

    floatx4 acc[8][4];
#pragma unroll
    for (int i = 0; i < 8; ++i)
#pragma unroll
        for (int j = 0; j < 4; ++j) acc[i][j] = (floatx4){0.f, 0.f, 0.f, 0.f};

    const int fr = lane & 15;
    const int kb = lane >> 4;
    const int sw0 = kb ^ (fr & 7);
    const int a0 = (wr * 128 + fr) * 64 + sw0 * 8;
    const int a1 = a0 ^ 32;
    const int b0 = 16384 + (wc * 64 + fr) * 64 + sw0 * 8;
    const int b1 = b0 ^ 32;

    const int sr = lane >> 3;
    const int sswz = (lane & 7) ^ sr;
    const u16* pA = A + (m0 + w * 8 + sr) * K + sswz * 8;
    const u16* pB = Bt + (n0 + w * 8 + sr) * K + sswz * 8;

#define ST2A(bufb, kt, h, l)                                                        \
    __builtin_amdgcn_global_load_lds(                                               \
        GCAST(pA + (size_t)((h) * 128 + (l) * 64) * K + (kt) * 64),                 \
        LCAST(smem16 + (bufb) + (h) * 8192 + (l) * 4096 + w * 512), 16, 0, 0)
#define ST2B(bufb, kt, h, l)                                                        \
    __builtin_amdgcn_global_load_lds(                                               \
        GCAST(pB + (size_t)((h) * 128 + (l) * 64) * K + (kt) * 64),                 \
        LCAST(smem16 + (bufb) + 16384 + (h) * 8192 + (l) * 4096 + w * 512), 16, 0, 0)

    short8 af[2][4], ba[2][2], bb[2][2];
#define RDA2(bufb, mh)                                                  \
    do {                                                                \
        _Pragma("unroll") for (int i_ = 0; i_ < 4; ++i_) {              \
            af[0][i_] = LDS8((bufb) + a0 + ((mh) * 4 + i_) * 1024);     \
            af[1][i_] = LDS8((bufb) + a1 + ((mh) * 4 + i_) * 1024);     \
        }                                                               \
    } while (0)
#define RDB2(bufb, BF, nh)                                                  \
    do {                                                                    \
        _Pragma("unroll") for (int j_ = 0; j_ < 2; ++j_) {                  \
            BF[0][j_] = LDS8((bufb) + b0 + ((nh) * 2 + j_) * 1024);         \
            BF[1][j_] = LDS8((bufb) + b1 + ((nh) * 2 + j_) * 1024);         \
        }                                                                   \
    } while (0)
#define MM2(IB, JB, BF)                                                                      \
    do {                                                                                     \
        __builtin_amdgcn_s_setprio(1);                                                       \
        _Pragma("unroll") for (int i_ = 0; i_ < 4; ++i_)                                     \
            _Pragma("unroll") for (int j_ = 0; j_ < 2; ++j_) {                               \
            acc[(IB) + i_][(JB) + j_] = __builtin_amdgcn_mfma_f32_16x16x32_bf16(             \
                af[0][i_], BF[0][j_], acc[(IB) + i_][(JB) + j_], 0, 0, 0);                   \
            acc[(IB) + i_][(JB) + j_] = __builtin_amdgcn_mfma_f32_16x16x32_bf16(             \
                af[1][i_], BF[1][j_], acc[(IB) + i_][(JB) + j_], 0, 0, 0);                   \
        }                                                                                    \
        __builtin_amdgcn_s_setprio(0);                                                       \
    } while (0)

#define ITER2(t, FULL, G4, G8)                                                               \
    do {                                                                                     \
        /* ph1 */ RDA2(X1, 0); RDB2(X1, ba, 0);                                              \
        ST2A(Y1, (t) + 1, 0, 0); ST2A(Y1, (t) + 1, 0, 1);                                    \
        BAR(); LGKM0(); MM2(0, 0, ba); BAR();                                                \
        /* ph2 */ RDB2(X1, bb, 1);                                                           \
        ST2A(Y1, (t) + 1, 1, 0); ST2A(Y1, (t) + 1, 1, 1);                                    \
        BAR(); LGKM0(); MM2(0, 2, bb); BAR();                                                \
        /* ph3 */ RDA2(X1, 1);                                                               \
        if (FULL) { ST2B(X1, (t) + 2, 0, 0); ST2B(X1, (t) + 2, 0, 1); }                      \
        BAR(); LGKM0(); MM2(4, 0, ba); BAR();                                                \
        /* ph4 */                                                                            \
        if (FULL) { ST2B(X1, (t) + 2, 1, 0); ST2B(X1, (t) + 2, 1, 1); }                      \
        VMCNT(G4); BAR(); MM2(4, 2, bb); BAR();                                              \
        /* ph5 */ RDA2(Y1, 0); RDB2(Y1, ba, 0);                                              \
        if (FULL) { ST2A(X1, (t) + 2, 0, 0); ST2A(X1, (t) + 2, 0, 1); }                      \
        BAR(); LGKM0(); MM2(0, 0, ba); BAR();                                                \
        /* ph6 */ RDB2(Y1, bb, 1);                                                           \
        if (FULL) { ST2A(X1, (t) + 2, 1, 0); ST2A(X1, (t) + 2, 1, 1); }                      \
        BAR(); LGKM0(); MM2(0, 2, bb); BAR();                                                \
        /* ph7 */ RDA2(Y1, 1);                                                               \
        if (FULL) { ST2B(Y1, (t) + 3, 0, 0); ST2B(Y1, (t) + 3, 0, 1); }                      \
        BAR(); LGKM0(); MM2(4, 0, ba); BAR();                                                \
        /* ph8 */                                                                            \
        if (FULL) { ST2B(Y1, (t) + 3, 1, 0); ST2B(Y1, (t) + 3, 1, 1); }                      \
        VMCNT(G8); BAR(); MM2(4, 2, bb); BAR();                                              \
    } while (0)

    // prologue: 6 half-tiles; vmcnt(4) -> tile0's 4 halves landed
    ST2B(X1, 0, 0, 0); ST2B(X1, 0, 0, 1);  // B0(0)
    ST2B(X1, 0, 1, 0); ST2B(X1, 0, 1, 1);  // B1(0)
    ST2A(X1, 0, 0, 0); ST2A(X1, 0, 0, 1);  // A0(0)
    ST2A(X1, 0, 1, 0); ST2A(X1, 0, 1, 1);  // A1(0)
    ST2B(Y1, 1, 0, 0); ST2B(Y1, 1, 0, 1);  // B0(1)
    ST2B(Y1, 1, 1, 0); ST2B(Y1, 1, 1, 1);  // B1(1)
    VMCNT(4); BAR();
#pragma unroll 1
    for (int it = 0; it < 15; ++it) ITER2(2 * it, 1, 4, 4);
    ITER2(30, 0, 0, 4);  // tiles 30,31; ph1/ph2 stage A(31); ph4 drains all

    const int r0row = (lane >> 4) * 4;
#pragma unroll
    for (int i = 0; i < 8; ++i)
#pragma unroll
        for (int r = 0; r < 4; ++r) {
            size_t row = m0 + wr * 128 + i * 16 + r0row + r;
#pragma unroll
            for (int j = 0; j < 4; ++j) {
                size_t col = n0 + wc * 64 + j * 16 + fr;
                C[row * N + col] = acc[i][j][r];
            }
        }
#undef ST2A
#undef ST2B
#undef RDA2
#undef RDB2
#undef MM2
#undef ITER2
}

// ============================================================
// Phase B: carry scan over 32 chunk summaries per (batch, channel) chain.
// ============================================================
__global__ __launch_bounds__(64) void scan_carry(const float2* __restrict__ sumAV,
                                                 float* __restrict__ carry) {
    const int g = blockIdx.x * 64 + threadIdx.x;  // 0..8191
    const int b = g >> 11, c = g & 2047;
    float h = 0.f;
#pragma unroll 8
    for (int ch = 0; ch < NCHUNK; ++ch) {
        float2 s = sumAV[(size_t)(b * NCHUNK + ch) * 2048 + c];
        carry[(size_t)(b * NCHUNK + ch) * 2048 + c] = h;
        h = fmaf(s.x, h, s.y);
    }
}

// ============================================================
// Phase C: replay chunk from packed (a,v), carry-in, emit h bf16.
// batch-4 prefetch (4 x 8B loads in flight per thread).
// grid (4, NCHUNK, BATCH) x 256; thread -> 2 channels.
// ============================================================
__global__ __launch_bounds__(256) void scan_apply(const uint32_t* __restrict__ av,
                                                  const float* __restrict__ carry,
                                                  uint32_t* __restrict__ hbuf) {
    const int b = blockIdx.z, ch = blockIdx.y;
    const int c2 = blockIdx.x * 256 + threadIdx.x;  // channel-pair 0..1023
    const size_t rowbase = (size_t)b * SEQ + (size_t)ch * CLEN;
    const uint32_t* p = av + rowbase * 2048 + c2 * 2;
    uint32_t* q = hbuf + rowbase * 1024 + c2;
    const float2 cin = ((const float2*)carry)[(size_t)(b * NCHUNK + ch) * 1024 + c2];
    float h0 = cin.x, h1 = cin.y;

    uint2 buf[4];
#pragma unroll
    for (int t = 0; t < 4; ++t) buf[t] = *(const uint2*)(p + (size_t)t * 2048);

    for (int j0 = 0; j0 < CLEN; j0 += 4) {
        uint2 nxt[4];
        if (j0 + 4 < CLEN) {
#pragma unroll
            for (int t = 0; t < 4; ++t)
                nxt[t] = *(const uint2*)(p + (size_t)(j0 + 4 + t) * 2048);
        }
#pragma unroll
        for (int t = 0; t < 4; ++t) {
            float a0 = bflo(buf[t].x), v0 = bfhi(buf[t].x);
            float a1 = bflo(buf[t].y), v1 = bfhi(buf[t].y);
            h0 = fmaf(a0, h0, v0);
            h1 = fmaf(a1, h1, v1);
            q[(size_t)(j0 + t) * 1024] = f2bf_bits(h0) | (f2bf_bits(h1) << 16);
        }
#pragma unroll
        for (int t = 0; t < 4; ++t) buf[t] = nxt[t];
    }
}

// ============================================================
extern "C" void kernel_launch(void* const* d_in, const int* in_sizes, int n_in,
                              void* d_out, int out_size, void* d_ws, size_t ws_size,
                              hipStream_t stream) {
    const float* x = (const float*)d_in[0];     // [16384,1024]
    const float* Whg = (const float*)d_in[1];   // [1024,4096]
    const float* Wout = (const float*)d_in[2];  // [2048,1024]

    char* ws = (char*)d_ws;
    size_t off = 0;
    u16* xb = (u16*)(ws + off);        off += (size_t)M_TOTAL * DIMX * 2;          // 33.6 MB
    u16* whgt = (u16*)(ws + off);      off += (size_t)N_HG * DIMX * 2;             // 8.4 MB
    u16* woutt = (u16*)(ws + off);     off += (size_t)DIMX * DIM_INNER * 2;        // 4.2 MB
    uint32_t* av = (uint32_t*)(ws + off); off += (size_t)M_TOTAL * DIM_INNER * 4;  // 134.2 MB
    uint32_t* hbuf = (uint32_t*)(ws + off); off += (size_t)M_TOTAL * DIM_INNER * 2; // 67.1 MB
    float2* sumAV = (float2*)(ws + off); off += (size_t)BATCH * NCHUNK * DIM_INNER * 8; // 2.1 MB
    // carry (1 MB) aliases whgt: whgt dead after gemm1_k (stream-ordered).
    float* carry = (float*)whgt;

    // 1. fused prep
    prep<<<2048 + 1024 + 512, 256, 0, stream>>>(x, Whg, Wout, xb, whgt, woutt);

    // 2. GEMM1 fused (8-phase): av + per-chunk summaries
    gemm1_k<<<dim3(16, 64), 512, 0, stream>>>(xb, whgt, av, sumAV);

    // 3. carry scan (chains of 32) + replay
    scan_carry<<<128, 64, 0, stream>>>(sumAV, carry);
    scan_apply<<<dim3(4, NCHUNK, BATCH), 256, 0, stream>>>(av, carry, hbuf);

    // 4. GEMM2 (8-phase): out = h @ Wout (fp32 out), 256x256 tiles
    gemm2_k<<<dim3(DIMX / 256, M_TOTAL / 256), 512, 0, stream>>>((const u16*)hbuf, woutt, (float*)d_out);
}

// Round 4
// 371.051 us; speedup vs baseline: 1.1287x; 1.0132x over previous
//
#include <hip/hip_runtime.h>
#include <stdint.h>

// ---- problem constants ----
#define DIMX 1024
#define DIM_INNER 2048
#define BATCH 4
#define SEQ 4096
#define M_TOTAL (BATCH * SEQ)   // 16384
#define N_HG (2 * DIM_INNER)    // 4096
#define NCHUNK 32               // chunks along S
#define CLEN 128                // steps per chunk

typedef unsigned short u16;
typedef __attribute__((ext_vector_type(8))) short short8;   // 8 x bf16 MFMA frag
typedef __attribute__((ext_vector_type(4))) float floatx4;  // MFMA acc

// ---- bf16 helpers (bit-level, RNE) ----
__device__ __forceinline__ float bflo(uint32_t u) { return __uint_as_float(u << 16); }
__device__ __forceinline__ float bfhi(uint32_t u) { return __uint_as_float(u & 0xffff0000u); }
__device__ __forceinline__ uint32_t f2bf_bits(float f) {
    uint32_t u = __float_as_uint(f);
    return (u + 0x7fffu + ((u >> 16) & 1u)) >> 16;  // round-to-nearest-even
}

#define GCAST(p) (const __attribute__((address_space(1))) uint32_t*)(const void*)(p)
#define LCAST(p) (__attribute__((address_space(3))) uint32_t*)(void*)(p)
// raw barrier + IR-level fence (plain LDS loads may not cross)
#define BAR()                                          \
    do {                                               \
        __builtin_amdgcn_s_barrier();                  \
        asm volatile("" ::: "memory");                 \
    } while (0)
// drain this wave's ds_reads before the phase's MFMA + pin scheduling (rule #18)
#define LGKM0()                                                  \
    do {                                                         \
        asm volatile("s_waitcnt lgkmcnt(0)" ::: "memory");       \
        __builtin_amdgcn_sched_barrier(0);                       \
    } while (0)
#define VMCNT_(n) asm volatile("s_waitcnt vmcnt(" #n ")" ::: "memory")
#define VMCNT(n) VMCNT_(n)

// ============================================================
// prep kernel: fuses x-cast + Whg transpose + Wout transpose. (unchanged)
// ============================================================
__global__ __launch_bounds__(256) void prep(const float* __restrict__ x,
                                            const float* __restrict__ Whg,
                                            const float* __restrict__ Wout,
                                            u16* __restrict__ xb,
                                            u16* __restrict__ whgt,
                                            u16* __restrict__ woutt) {
    __shared__ float tile[64][65];
    const int bid = blockIdx.x;
    const int tid = threadIdx.x;
    if (bid < 2048) {
        const int n4 = M_TOTAL * DIMX / 4;
        const float4* in4 = (const float4*)x;
        ushort4* out4 = (ushort4*)xb;
        for (int i = bid * 256 + tid; i < n4; i += 2048 * 256) {
            float4 v = in4[i];
            ushort4 o;
            o.x = (u16)f2bf_bits(v.x);
            o.y = (u16)f2bf_bits(v.y);
            o.z = (u16)f2bf_bits(v.z);
            o.w = (u16)f2bf_bits(v.w);
            out4[i] = o;
        }
        return;
    }
    const float* in;
    u16* out;
    int R, C, tb;
    if (bid < 3072) {
        in = Whg; out = whgt; R = DIMX; C = N_HG; tb = bid - 2048;
    } else {
        in = Wout; out = woutt; R = DIM_INNER; C = DIMX; tb = bid - 3072;
    }
    const int tilesx = C / 64;
    const int c0 = (tb % tilesx) * 64, r0 = (tb / tilesx) * 64;
    const int tx = tid & 63, ty = tid >> 6;  // 64 x 4
#pragma unroll
    for (int i = ty; i < 64; i += 4)
        tile[i][tx] = in[(size_t)(r0 + i) * C + c0 + tx];
    __syncthreads();
#pragma unroll
    for (int i = ty; i < 64; i += 4)
        out[(size_t)(c0 + i) * R + r0 + tx] = (u16)f2bf_bits(tile[tx][i]);
}

// ============================================================
// GEMM1 fused (R13 = R12 + XCD-aware block remap).
// 8-phase 256-wide template (T2+T3+T4+T5).
// BM=256 rows x BN=128 ch x {h,g}, BK=64, 2 LDS buffers (2x64KB),
// 512 thr / 8 waves (wr=wave>>2 row-half, wc=wave&3 ch-quarter).
// XCD remap (T1): wgid -> xcd=wgid&7, idx=wgid>>3, x'=idx&15,
// y'=(idx>>4)*8+xcd. Each XCD owns y=xcd (mod 8) x all 16 x-tiles;
// the 32 co-resident blocks/XCD = 16 x * 2 y -> shared A-panels (2x512KB)
// are L2-resident, A loads become ~200cyc L2 hits -> the 8-phase's
// 3-phase gate distance covers the latency (same regime as gemm2).
// Stage slots / gates unchanged from R12 (audited, ran correct).
// grid 1024 blocks (1D).
// ============================================================
__global__ __launch_bounds__(512, 2) void gemm1_k(const u16* __restrict__ A,
                                                  const u16* __restrict__ Bt,
                                                  uint32_t* __restrict__ av,
                                                  float2* __restrict__ sumAV) {
    __shared__ alignas(16) u16 smem16[65536];  // 128 KB
    const int tid = threadIdx.x;
    const int lane = tid & 63;
    const int w = tid >> 6;
    const int wr = w >> 2;
    const int wc = w & 3;
    // T1 XCD-aware bijective remap (1024 blocks, 8 XCDs)
    const int wgid = blockIdx.x;
    const int xcd = wgid & 7;
    const int idx = wgid >> 3;          // 0..127
    const int xt = idx & 15;            // column tile 0..15
    const int yt = (idx >> 4) * 8 + xcd; // row tile 0..63, yt%8 == xcd
    const size_t m0 = (size_t)yt * 256;
    const int n0 = xt * 128;
#define X1 0
#define Y1 32768

    floatx4 acch[8][2], accg[8][2];
#pragma unroll
    for (int i = 0; i < 8; ++i)
#pragma unroll
        for (int j = 0; j < 2; ++j) {
            acch[i][j] = (floatx4){0.f, 0.f, 0.f, 0.f};
            accg[i][j] = (floatx4){0.f, 0.f, 0.f, 0.f};
        }

    // fragment addressing (u16 indices); row stride 64 u16, slot = 8 u16 (16B)
    const int fr = lane & 15;
    const int kb = lane >> 4;
    const int sw0 = kb ^ (fr & 7);                       // swizzled slot, kstep 0
    const int a0 = (wr * 128 + fr) * 64 + sw0 * 8;       // kstep1 = a0 ^ 32
    const int a1 = a0 ^ 32;
    const int b0 = 16384 + (wc * 32 + fr) * 64 + sw0 * 8;
    const int b1 = b0 ^ 32;

    // staging: lane covers (row = 8w + lane>>3, slot' = lane&7); global slot
    // = slot' ^ (row&7) = (lane&7)^(lane>>3). LDS dest stays linear.
    const int sr = lane >> 3;
    const int sswz = (lane & 7) ^ sr;
    const u16* pA = A + (m0 + w * 8 + sr) * DIMX + sswz * 8;
    const u16* pBh = Bt + ((size_t)(n0 + w * 8 + sr)) * DIMX + sswz * 8;
    const u16* pBg = pBh + (size_t)DIM_INNER * DIMX;

#define ST1A(bufb, kt, h, l)                                                        \
    __builtin_amdgcn_global_load_lds(                                               \
        GCAST(pA + (size_t)((h) * 128 + (l) * 64) * DIMX + (kt) * 64),              \
        LCAST(smem16 + (bufb) + (h) * 8192 + (l) * 4096 + w * 512), 16, 0, 0)
#define ST1H(bufb, kt, l)                                                           \
    __builtin_amdgcn_global_load_lds(                                               \
        GCAST(pBh + (size_t)((l) * 64) * DIMX + (kt) * 64),                         \
        LCAST(smem16 + (bufb) + 16384 + (l) * 4096 + w * 512), 16, 0, 0)
#define ST1G(bufb, kt, l)                                                           \
    __builtin_amdgcn_global_load_lds(                                               \
        GCAST(pBg + (size_t)((l) * 64) * DIMX + (kt) * 64),                         \
        LCAST(smem16 + (bufb) + 24576 + (l) * 4096 + w * 512), 16, 0, 0)

#define LDS8(idx) (*(const short8*)(smem16 + (idx)))
    short8 af[2][4], bh[2][2], bg[2][2];
#define RDA1(bufb, mh)                                                  \
    do {                                                                \
        _Pragma("unroll") for (int i_ = 0; i_ < 4; ++i_) {              \
            af[0][i_] = LDS8((bufb) + a0 + ((mh) * 4 + i_) * 1024);     \
            af[1][i_] = LDS8((bufb) + a1 + ((mh) * 4 + i_) * 1024);     \
        }                                                               \
    } while (0)
#define RDBH1(bufb)                                                     \
    do {                                                                \
        _Pragma("unroll") for (int j_ = 0; j_ < 2; ++j_) {              \
            bh[0][j_] = LDS8((bufb) + b0 + j_ * 1024);                  \
            bh[1][j_] = LDS8((bufb) + b1 + j_ * 1024);                  \
        }                                                               \
    } while (0)
#define RDBG1(bufb)                                                     \
    do {                                                                \
        _Pragma("unroll") for (int j_ = 0; j_ < 2; ++j_) {              \
            bg[0][j_] = LDS8((bufb) + b0 + 8192 + j_ * 1024);           \
            bg[1][j_] = LDS8((bufb) + b1 + 8192 + j_ * 1024);           \
        }                                                               \
    } while (0)
#define MM1(ACC, IB, BF)                                                                     \
    do {                                                                                     \
        __builtin_amdgcn_s_setprio(1);                                                       \
        _Pragma("unroll") for (int i_ = 0; i_ < 4; ++i_)                                     \
            _Pragma("unroll") for (int j_ = 0; j_ < 2; ++j_) {                               \
            ACC[(IB) + i_][j_] = __builtin_amdgcn_mfma_f32_16x16x32_bf16(                    \
                af[0][i_], BF[0][j_], ACC[(IB) + i_][j_], 0, 0, 0);                          \
            ACC[(IB) + i_][j_] = __builtin_amdgcn_mfma_f32_16x16x32_bf16(                    \
                af[1][i_], BF[1][j_], ACC[(IB) + i_][j_], 0, 0, 0);                          \
        }                                                                                    \
        __builtin_amdgcn_s_setprio(0);                                                       \
    } while (0)

#define ITER1(t, FULL, G4, G8)                                                               \
    do {                                                                                     \
        /* ph1: q(mh0,h) of tile t (X) */                                                    \
        RDA1(X1, 0); RDBH1(X1);                                                              \
        ST1A(Y1, (t) + 1, 1, 0); ST1A(Y1, (t) + 1, 1, 1);                                    \
        BAR(); LGKM0(); MM1(acch, 0, bh); BAR();                                             \
        /* ph2: q(mh0,g) */                                                                  \
        RDBG1(X1);                                                                           \
        if (FULL) { ST1H(X1, (t) + 2, 0); ST1H(X1, (t) + 2, 1); }                            \
        BAR(); LGKM0(); MM1(accg, 0, bg); BAR();                                             \
        /* ph3: q(mh1,h) */                                                                  \
        RDA1(X1, 1);                                                                         \
        if (FULL) { ST1G(X1, (t) + 2, 0); ST1G(X1, (t) + 2, 1); }                            \
        BAR(); LGKM0(); MM1(acch, 4, bh); BAR();                                             \
        /* ph4: q(mh1,g); gate */                                                            \
        if (FULL) { ST1A(X1, (t) + 2, 0, 0); ST1A(X1, (t) + 2, 0, 1); }                      \
        VMCNT(G4); BAR(); MM1(accg, 4, bg); BAR();                                           \
        /* ph5: q(mh0,h) of tile t+1 (Y) */                                                  \
        RDA1(Y1, 0); RDBH1(Y1);                                                              \
        if (FULL) { ST1A(X1, (t) + 2, 1, 0); ST1A(X1, (t) + 2, 1, 1); }                      \
        BAR(); LGKM0(); MM1(acch, 0, bh); BAR();                                             \
        /* ph6: q(mh0,g) */                                                                  \
        RDBG1(Y1);                                                                           \
        if (FULL) { ST1H(Y1, (t) + 3, 0); ST1H(Y1, (t) + 3, 1); }                            \
        BAR(); LGKM0(); MM1(accg, 0, bg); BAR();                                             \
        /* ph7: q(mh1,h) */                                                                  \
        RDA1(Y1, 1);                                                                         \
        if (FULL) { ST1G(Y1, (t) + 3, 0); ST1G(Y1, (t) + 3, 1); }                            \
        BAR(); LGKM0(); MM1(acch, 4, bh); BAR();                                             \
        /* ph8: q(mh1,g); gate */                                                            \
        if (FULL) { ST1A(Y1, (t) + 3, 0, 0); ST1A(Y1, (t) + 3, 0, 1); }                      \
        VMCNT(G8); BAR(); MM1(accg, 4, bg); BAR();                                           \
    } while (0)

    // prologue: 7 half-tiles; vmcnt(6) -> tile0's 4 halves landed
    ST1H(X1, 0, 0); ST1H(X1, 0, 1);        // Bh(0)
    ST1G(X1, 0, 0); ST1G(X1, 0, 1);        // Bg(0)
    ST1A(X1, 0, 0, 0); ST1A(X1, 0, 0, 1);  // A0(0)
    ST1A(X1, 0, 1, 0); ST1A(X1, 0, 1, 1);  // A1(0)
    ST1H(Y1, 1, 0); ST1H(Y1, 1, 1);        // Bh(1)
    ST1G(Y1, 1, 0); ST1G(Y1, 1, 1);        // Bg(1)
    ST1A(Y1, 1, 0, 0); ST1A(Y1, 1, 0, 1);  // A0(1)
    VMCNT(6); BAR();
#pragma unroll 1
    for (int it = 0; it < 7; ++it) ITER1(2 * it, 1, 6, 6);
    ITER1(14, 0, 0, 6);  // tiles 14,15; ph1 stages A1(15); ph4 drains all

    __syncthreads();  // staging LDS dead; reuse as avl [256][128] u32 = 128 KB

    uint32_t* avl = (uint32_t*)smem16;
    const int r0row = (lane >> 4) * 4;
#pragma unroll
    for (int i = 0; i < 8; ++i) {
#pragma unroll
        for (int r = 0; r < 4; ++r) {
            const int row = wr * 128 + i * 16 + r0row + r;
#pragma unroll
            for (int j = 0; j < 2; ++j) {
                const int col = wc * 32 + j * 16 + fr;
                float h = acch[i][j][r];
                float g = accg[i][j][r];
                g = fminf(fmaxf(g, -30.f), 30.f);
                float e = __expf(-g);
                float z = 1.f / (1.f + e);
                float a = e * z;                       // 1 - sigmoid(g)
                float v = z * (fmaxf(h, 0.f) + 0.5f);  // sigmoid(g)*(relu(h)+0.5)
                uint32_t pk = f2bf_bits(a) | (f2bf_bits(v) << 16);
                avl[row * 128 + col] = pk;
                av[(m0 + row) * 2048 + n0 + col] = pk;
            }
        }
    }
    __syncthreads();

    // in-block chunk-summary scan: block covers 2 chunks of 128 rows
    const int chl = tid >> 8;  // chunk-local 0/1
    const int t2 = tid & 255;
    const int col = t2 & 127;
    const int rlo = (t2 >> 7) * 64;
    float Aa = 1.f, Vv = 0.f;
#pragma unroll 8
    for (int j = 0; j < 64; ++j) {
        uint32_t pk = avl[(chl * 128 + rlo + j) * 128 + col];
        float a = bflo(pk), v = bfhi(pk);
        Vv = fmaf(a, Vv, v);
        Aa *= a;
    }
    __syncthreads();
    if (rlo == 0) {
        avl[chl * 256 + col] = __float_as_uint(Aa);
        avl[chl * 256 + 128 + col] = __float_as_uint(Vv);
    }
    __syncthreads();
    if (rlo != 0) {
        float Al = __uint_as_float(avl[chl * 256 + col]);
        float Vl = __uint_as_float(avl[chl * 256 + 128 + col]);
        float At = Al * Aa;
        float Vt = fmaf(Aa, Vl, Vv);
        const int chunk = (int)(m0 >> 7) + chl;  // global chunk id = b*32+ch
        sumAV[(size_t)chunk * 2048 + n0 + col] = (float2){At, Vt};
    }
#undef ST1A
#undef ST1H
#undef ST1G
#undef RDA1
#undef RDBH1
#undef RDBG1
#undef MM1
#undef ITER1
}

// ============================================================
// GEMM2 (unchanged from R12 — measured ~1500 TF, template-class):
// 8-phase 256x256 template. BK=64, 2x64KB buffers,
// 512 thr / 8 waves; wave = 128 rows x 64 cols, acc[8][4] = 128 VGPR.
// Quadrants {mh}x{nh}. Stage slots (iter i, t=2i):
//  ph1: A0(t+1)->Y  ph2: A1(t+1)->Y   [Y-A last read prev ph7]
//  ph3: B0(t+2)->X  ph4: B1(t+2)->X   [X-B read ph1,ph2]
//  ph5: A0(t+2)->X  ph6: A1(t+2)->X   [X-A read ph1,ph3]
//  ph7: B0(t+3)->Y  ph8: B1(t+3)->Y   [Y-B read ph5,ph6]
// Gates vmcnt(4) at ph4 (covers through ph2: A(t+1)) and ph8 (through
// ph6: A(t+2)). grid (4, 64) = 256 blocks.
// ============================================================
__global__ __launch_bounds__(512, 2) void gemm2_k(const u16* __restrict__ A,
                                                  const u16* __restrict__ Bt,
                                                  float* __restrict__ C) {
    const int N = DIMX, K = DIM_INNER;
    __shared__ alignas(16) u16 smem16[65536];  // 128 KB
    const int tid = threadIdx.x;
    const int lane = tid & 63;
    const int w = tid >> 6;
    const int wr = w >> 2;
    const int wc = w & 3;
    const size_t m0 = (size_t)blockIdx.y * 256;
    const size_t n0 = (size_t)blockIdx.x * 256;

    floatx4 acc[8][4];
#pragma unroll
    for (int i = 0; i < 8; ++i)
#pragma unroll
        for (int j = 0; j < 4; ++j) acc[i][j] = (floatx4){0.f, 0.f, 0.f, 0.f};

    const int fr = lane & 15;
    const int kb = lane >> 4;
    const int sw0 = kb ^ (fr & 7);
    const int a0 = (wr * 128 + fr) * 64 + sw0 * 8;
    const int a1 = a0 ^ 32;
    const int b0 = 16384 + (wc * 64 + fr) * 64 + sw0 * 8;
    const int b1 = b0 ^ 32;

    const int sr = lane >> 3;
    const int sswz = (lane & 7) ^ sr;
    const u16* pA = A + (m0 + w * 8 + sr) * K + sswz * 8;
    const u16* pB = Bt + (n0 + w * 8 + sr) * K + sswz * 8;

#define ST2A(bufb, kt, h, l)                                                        \
    __builtin_amdgcn_global_load_lds(                                               \
        GCAST(pA + (size_t)((h) * 128 + (l) * 64) * K + (kt) * 64),                 \
        LCAST(smem16 + (bufb) + (h) * 8192 + (l) * 4096 + w * 512), 16, 0, 0)
#define ST2B(bufb, kt, h, l)                                                        \
    __builtin_amdgcn_global_load_lds(                                               \
        GCAST(pB + (size_t)((h) * 128 + (l) * 64) * K + (kt) * 64),                 \
        LCAST(smem16 + (bufb) + 16384 + (h) * 8192 + (l) * 4096 + w * 512), 16, 0, 0)

    short8 af[2][4], ba[2][2], bb[2][2];
#define RDA2(bufb, mh)                                                  \
    do {                                                                \
        _Pragma("unroll") for (int i_ = 0; i_ < 4; ++i_) {              \
            af[0][i_] = LDS8((bufb) + a0 + ((mh) * 4 + i_) * 1024);     \
            af[1][i_] = LDS8((bufb) + a1 + ((mh) * 4 + i_) * 1024);     \
        }                                                               \
    } while (0)
#define RDB2(bufb, BF, nh)                                                  \
    do {                                                                    \
        _Pragma("unroll") for (int j_ = 0; j_ < 2; ++j_) {                  \
            BF[0][j_] = LDS8((bufb) + b0 + ((nh) * 2 + j_) * 1024);         \
            BF[1][j_] = LDS8((bufb) + b1 + ((nh) * 2 + j_) * 1024);         \
        }                                                                   \
    } while (0)
#define MM2(IB, JB, BF)                                                                      \
    do {                                                                                     \
        __builtin_amdgcn_s_setprio(1);                                                       \
        _Pragma("unroll") for (int i_ = 0; i_ < 4; ++i_)                                     \
            _Pragma("unroll") for (int j_ = 0; j_ < 2; ++j_) {                               \
            acc[(IB) + i_][(JB) + j_] = __builtin_amdgcn_mfma_f32_16x16x32_bf16(             \
                af[0][i_], BF[0][j_], acc[(IB) + i_][(JB) + j_], 0, 0, 0);                   \
            acc[(IB) + i_][(JB) + j_] = __builtin_amdgcn_mfma_f32_16x16x32_bf16(             \
                af[1][i_], BF[1][j_], acc[(IB) + i_][(JB) + j_], 0, 0, 0);                   \
        }                                                                                    \
        __builtin_amdgcn_s_setprio(0);                                                       \
    } while (0)

#define ITER2(t, FULL, G4, G8)                                                               \
    do {                                                                                     \
        /* ph1 */ RDA2(X1, 0); RDB2(X1, ba, 0);                                              \
        ST2A(Y1, (t) + 1, 0, 0); ST2A(Y1, (t) + 1, 0, 1);                                    \
        BAR(); LGKM0(); MM2(0, 0, ba); BAR();                                                \
        /* ph2 */ RDB2(X1, bb, 1);                                                           \
        ST2A(Y1, (t) + 1, 1, 0); ST2A(Y1, (t) + 1, 1, 1);                                    \
        BAR(); LGKM0(); MM2(0, 2, bb); BAR();                                                \
        /* ph3 */ RDA2(X1, 1);                                                               \
        if (FULL) { ST2B(X1, (t) + 2, 0, 0); ST2B(X1, (t) + 2, 0, 1); }                      \
        BAR(); LGKM0(); MM2(4, 0, ba); BAR();                                                \
        /* ph4 */                                                                            \
        if (FULL) { ST2B(X1, (t) + 2, 1, 0); ST2B(X1, (t) + 2, 1, 1); }                      \
        VMCNT(G4); BAR(); MM2(4, 2, bb); BAR();                                              \
        /* ph5 */ RDA2(Y1, 0); RDB2(Y1, ba, 0);                                              \
        if (FULL) { ST2A(X1, (t) + 2, 0, 0); ST2A(X1, (t) + 2, 0, 1); }                      \
        BAR(); LGKM0(); MM2(0, 0, ba); BAR();                                                \
        /* ph6 */ RDB2(Y1, bb, 1);                                                           \
        if (FULL) { ST2A(X1, (t) + 2, 1, 0); ST2A(X1, (t) + 2, 1, 1); }                      \
        BAR(); LGKM0(); MM2(0, 2, bb); BAR();                                                \
        /* ph7 */ RDA2(Y1, 1);                                                               \
        if (FULL) { ST2B(Y1, (t) + 3, 0, 0); ST2B(Y1, (t) + 3, 0, 1); }                      \
        BAR(); LGKM0(); MM2(4, 0, ba); BAR();                                                \
        /* ph8 */                                                                            \
        if (FULL) { ST2B(Y1, (t) + 3, 1, 0); ST2B(Y1, (t) + 3, 1, 1); }                      \
        VMCNT(G8); BAR(); MM2(4, 2, bb); BAR();                                              \
    } while (0)

    // prologue: 6 half-tiles; vmcnt(4) -> tile0's 4 halves landed
    ST2B(X1, 0, 0, 0); ST2B(X1, 0, 0, 1);  // B0(0)
    ST2B(X1, 0, 1, 0); ST2B(X1, 0, 1, 1);  // B1(0)
    ST2A(X1, 0, 0, 0); ST2A(X1, 0, 0, 1);  // A0(0)
    ST2A(X1, 0, 1, 0); ST2A(X1, 0, 1, 1);  // A1(0)
    ST2B(Y1, 1, 0, 0); ST2B(Y1, 1, 0, 1);  // B0(1)
    ST2B(Y1, 1, 1, 0); ST2B(Y1, 1, 1, 1);  // B1(1)
    VMCNT(4); BAR();
#pragma unroll 1
    for (int it = 0; it < 15; ++it) ITER2(2 * it, 1, 4, 4);
    ITER2(30, 0, 0, 4);  // tiles 30,31; ph1/ph2 stage A(31); ph4 drains all

    const int r0row = (lane >> 4) * 4;
#pragma unroll
    for (int i = 0; i < 8; ++i)
#pragma unroll
        for (int r = 0; r < 4; ++r) {
            size_t row = m0 + wr * 128 + i * 16 + r0row + r;
#pragma unroll
            for (int j = 0; j < 4; ++j) {
                size_t col = n0 + wc * 64 + j * 16 + fr;
                C[row * N + col] = acc[i][j][r];
            }
        }
#undef ST2A
#undef ST2B
#undef RDA2
#undef RDB2
#undef MM2
#undef ITER2
}

// ============================================================
// Phase B: carry scan over 32 chunk summaries per (batch, channel) chain.
// ============================================================
__global__ __launch_bounds__(64) void scan_carry(const float2* __restrict__ sumAV,
                                                 float* __restrict__ carry) {
    const int g = blockIdx.x * 64 + threadIdx.x;  // 0..8191
    const int b = g >> 11, c = g & 2047;
    float h = 0.f;
#pragma unroll 8
    for (int ch = 0; ch < NCHUNK; ++ch) {
        float2 s = sumAV[(size_t)(b * NCHUNK + ch) * 2048 + c];
        carry[(size_t)(b * NCHUNK + ch) * 2048 + c] = h;
        h = fmaf(s.x, h, s.y);
    }
}

// ============================================================
// Phase C: replay chunk from packed (a,v), carry-in, emit h bf16.
// batch-4 prefetch (4 x 8B loads in flight per thread).
// grid (4, NCHUNK, BATCH) x 256; thread -> 2 channels.
// ============================================================
__global__ __launch_bounds__(256) void scan_apply(const uint32_t* __restrict__ av,
                                                  const float* __restrict__ carry,
                                                  uint32_t* __restrict__ hbuf) {
    const int b = blockIdx.z, ch = blockIdx.y;
    const int c2 = blockIdx.x * 256 + threadIdx.x;  // channel-pair 0..1023
    const size_t rowbase = (size_t)b * SEQ + (size_t)ch * CLEN;
    const uint32_t* p = av + rowbase * 2048 + c2 * 2;
    uint32_t* q = hbuf + rowbase * 1024 + c2;
    const float2 cin = ((const float2*)carry)[(size_t)(b * NCHUNK + ch) * 1024 + c2];
    float h0 = cin.x, h1 = cin.y;

    uint2 buf[4];
#pragma unroll
    for (int t = 0; t < 4; ++t) buf[t] = *(const uint2*)(p + (size_t)t * 2048);

    for (int j0 = 0; j0 < CLEN; j0 += 4) {
        uint2 nxt[4];
        if (j0 + 4 < CLEN) {
#pragma unroll
            for (int t = 0; t < 4; ++t)
                nxt[t] = *(const uint2*)(p + (size_t)(j0 + 4 + t) * 2048);
        }
#pragma unroll
        for (int t = 0; t < 4; ++t) {
            float a0 = bflo(buf[t].x), v0 = bfhi(buf[t].x);
            float a1 = bflo(buf[t].y), v1 = bfhi(buf[t].y);
            h0 = fmaf(a0, h0, v0);
            h1 = fmaf(a1, h1, v1);
            q[(size_t)(j0 + t) * 1024] = f2bf_bits(h0) | (f2bf_bits(h1) << 16);
        }
#pragma unroll
        for (int t = 0; t < 4; ++t) buf[t] = nxt[t];
    }
}

// ============================================================
extern "C" void kernel_launch(void* const* d_in, const int* in_sizes, int n_in,
                              void* d_out, int out_size, void* d_ws, size_t ws_size,
                              hipStream_t stream) {
    const float* x = (const float*)d_in[0];     // [16384,1024]
    const float* Whg = (const float*)d_in[1];   // [1024,4096]
    const float* Wout = (const float*)d_in[2];  // [2048,1024]

    char* ws = (char*)d_ws;
    size_t off = 0;
    u16* xb = (u16*)(ws + off);        off += (size_t)M_TOTAL * DIMX * 2;          // 33.6 MB
    u16* whgt = (u16*)(ws + off);      off += (size_t)N_HG * DIMX * 2;             // 8.4 MB
    u16* woutt = (u16*)(ws + off);     off += (size_t)DIMX * DIM_INNER * 2;        // 4.2 MB
    uint32_t* av = (uint32_t*)(ws + off); off += (size_t)M_TOTAL * DIM_INNER * 4;  // 134.2 MB
    uint32_t* hbuf = (uint32_t*)(ws + off); off += (size_t)M_TOTAL * DIM_INNER * 2; // 67.1 MB
    float2* sumAV = (float2*)(ws + off); off += (size_t)BATCH * NCHUNK * DIM_INNER * 8; // 2.1 MB
    // carry (1 MB) aliases whgt: whgt dead after gemm1_k (stream-ordered).
    float* carry = (float*)whgt;

    // 1. fused prep
    prep<<<2048 + 1024 + 512, 256, 0, stream>>>(x, Whg, Wout, xb, whgt, woutt);

    // 2. GEMM1 fused (8-phase + XCD remap): av + per-chunk summaries
    gemm1_k<<<1024, 512, 0, stream>>>(xb, whgt, av, sumAV);

    // 3. carry scan (chains of 32) + replay
    scan_carry<<<128, 64, 0, stream>>>(sumAV, carry);
    scan_apply<<<dim3(4, NCHUNK, BATCH), 256, 0, stream>>>(av, carry, hbuf);

    // 4. GEMM2 (8-phase): out = h @ Wout (fp32 out), 256x256 tiles
    gemm2_k<<<dim3(DIMX / 256, M_TOTAL / 256), 512, 0, stream>>>((const u16*)hbuf, woutt, (float*)d_out);
}